// Round 9
// baseline (662.969 us; speedup 1.0000x reference)
//
#include <hip/hip_runtime.h>
#include <hip/hip_bf16.h>

#define N_NODES 19000
#define N_EDGES 600000
#define BATCH   4096
#define GNN_D   256
#define H_D     512
#define MID_D   2048
#define L_N     6
#define C_N     3
#define R_D     512
#define G_N     6640
#define LN_EPS  1e-5f
#define MAXDEG  128

typedef __attribute__((ext_vector_type(8))) short short8;
typedef __attribute__((ext_vector_type(4))) float f32x4;
typedef __hip_bfloat16 bf16;

// ---------------- merged weight conversion (7 dsts, 1 launch) ----------------
#define SEG0 32768                    // w_in   512*256/4
#define SEG1 (SEG0 + 1572864)         // fc1    6*2048*512/4
#define SEG2 (SEG1 + 1572864)         // fc2
#define SEG3 (SEG2 + 196608)          // wbil   3*512*512/4
#define SEG4 (SEG3 + 849920)          // gene   6640*512/4
#define SEG5 (SEG4 + 16384)           // wpost  256*256/4
#define SEG6 (SEG5 + 32768)           // wrn    256*512/4
#define CONV_TOT SEG6

__global__ void convert_weights_kernel(
    const float* __restrict__ w_in, const float* __restrict__ fc1,
    const float* __restrict__ fc2, const float* __restrict__ wbil,
    const float* __restrict__ gene, const float* __restrict__ wpost,
    const float* __restrict__ wroot, const float* __restrict__ wneigh,
    bf16* __restrict__ o_win, bf16* __restrict__ o_fc1, bf16* __restrict__ o_fc2,
    bf16* __restrict__ o_wbil, bf16* __restrict__ o_gene, bf16* __restrict__ o_wpost,
    bf16* __restrict__ o_wrn) {
  int i = blockIdx.x * blockDim.x + threadIdx.x;
  if (i >= CONV_TOT) return;
  const float* src;
  bf16* dst;
  if (i < SEG0)      { src = w_in  + (size_t)i * 4;            dst = o_win  + (size_t)i * 4; }
  else if (i < SEG1) { size_t j = i - SEG0; src = fc1  + j * 4; dst = o_fc1  + j * 4; }
  else if (i < SEG2) { size_t j = i - SEG1; src = fc2  + j * 4; dst = o_fc2  + j * 4; }
  else if (i < SEG3) { size_t j = i - SEG2; src = wbil + j * 4; dst = o_wbil + j * 4; }
  else if (i < SEG4) { size_t j = i - SEG3; src = gene + j * 4; dst = o_gene + j * 4; }
  else if (i < SEG5) { size_t j = i - SEG4; src = wpost+ j * 4; dst = o_wpost+ j * 4; }
  else {  // wrn: [256][512] = [w_root | w_neigh]
    int j = i - SEG5;
    int base = j * 4;
    int n = base >> 9;
    int k = base & 511;
    src = (k < GNN_D) ? (wroot + (size_t)n * GNN_D + k)
                      : (wneigh + (size_t)n * GNN_D + (k - GNN_D));
    dst = o_wrn + base;
  }
  float4 v = *(const float4*)src;
  dst[0] = __float2bfloat16(v.x);
  dst[1] = __float2bfloat16(v.y);
  dst[2] = __float2bfloat16(v.z);
  dst[3] = __float2bfloat16(v.w);
}

// ---------------- graph compaction kernels (unchanged, proven) ----------------
// init_meta also zeroes the 6 per-layer rowstat buffers (6*4096*2 floats)

__global__ void init_meta_kernel(int* __restrict__ flags, int* __restrict__ cursor,
                                 int* __restrict__ nuniq, float* __restrict__ rowstat) {
  int i = blockIdx.x * blockDim.x + threadIdx.x;
  if (i < N_NODES) flags[i] = 0;
  if (i < BATCH) cursor[i] = 0;
  if (i == 0) *nuniq = 0;
  const int RS_TOT = 6 * BATCH * 2;
#pragma unroll
  for (int j = 0; j < 3; ++j) {
    int k = i * 3 + j;
    if (k < RS_TOT) rowstat[k] = 0.f;
  }
}

__global__ void mark_needed_kernel(const int* __restrict__ idx, int* __restrict__ flags) {
  int i = blockIdx.x * blockDim.x + threadIdx.x;
  if (i < BATCH) {
    int id = idx[i];
    if (id >= 0) flags[id] = 1;
  }
}

__global__ void assign_slots_kernel(const int* __restrict__ flags, int* __restrict__ slot,
                                    int* __restrict__ uniq, int* __restrict__ nuniq) {
  int i = blockIdx.x * blockDim.x + threadIdx.x;
  if (i >= N_NODES) return;
  if (flags[i]) {
    int s = atomicAdd(nuniq, 1);
    slot[i] = s;
    uniq[s] = i;
  }
}

__global__ __launch_bounds__(256) void fill_edges_kernel(
    const int* __restrict__ ei, const float* __restrict__ ew,
    const int* __restrict__ flags, const int* __restrict__ slot,
    int* __restrict__ cursor, int* __restrict__ el_src, float* __restrict__ el_w) {
  int e = blockIdx.x * blockDim.x + threadIdx.x;
  if (e >= N_EDGES) return;
  int dst = ei[N_EDGES + e];
  if (!flags[dst]) return;
  int s = slot[dst];
  int p = atomicAdd(&cursor[s], 1);
  if (p < MAXDEG) {
    el_src[s * MAXDEG + p] = ei[e];
    el_w[s * MAXDEG + p] = ew[e];
  }
}

__global__ __launch_bounds__(256) void gather_nodes_kernel(
    const float* __restrict__ cache, const int* __restrict__ uniq,
    const int* __restrict__ cursor, const int* __restrict__ nuniq,
    const int* __restrict__ el_src, const float* __restrict__ el_w,
    bf16* __restrict__ compact2) {
  int s = blockIdx.x, t = threadIdx.x;
  bf16* row = compact2 + (size_t)s * (2 * GNN_D);
  if (s >= *nuniq) {
    row[t] = __float2bfloat16(0.f);
    row[GNN_D + t] = __float2bfloat16(0.f);
    return;
  }
  row[t] = __float2bfloat16(cache[(size_t)uniq[s] * GNN_D + t]);
  int deg = cursor[s];
  deg = (deg < MAXDEG) ? deg : MAXDEG;
  float acc = 0.f;
  for (int e = 0; e < deg; ++e) {
    int src = el_src[s * MAXDEG + e];
    float w = el_w[s * MAXDEG + e];
    acc += cache[(size_t)src * GNN_D + t] * w;
  }
  row[GNN_D + t] = __float2bfloat16(acc);
}

__global__ __launch_bounds__(256) void gather_ln_kernel(
    const float* __restrict__ embc, const int* __restrict__ slot,
    const float* __restrict__ fallback, const int* __restrict__ idx,
    const float* __restrict__ scale, const float* __restrict__ bias,
    bf16* __restrict__ out) {
  int b = blockIdx.x, t = threadIdx.x;
  int id = idx[b];
  float v = (id >= 0) ? embc[(size_t)slot[id] * GNN_D + t] : fallback[t];
  float s = v, q = v * v;
#pragma unroll
  for (int o = 32; o > 0; o >>= 1) { s += __shfl_down(s, o); q += __shfl_down(q, o); }
  __shared__ float ls[4], lq[4];
  int wv = t >> 6, ln = t & 63;
  if (ln == 0) { ls[wv] = s; lq[wv] = q; }
  __syncthreads();
  s = ls[0] + ls[1] + ls[2] + ls[3];
  q = lq[0] + lq[1] + lq[2] + lq[3];
  float mu = s * (1.f / GNN_D);
  float var = q * (1.f / GNN_D) - mu * mu;
  float r = rsqrtf(var + LN_EPS);
  out[(size_t)b * GNN_D + t] = __float2bfloat16((v - mu) * r * scale[t] + bias[t]);
}

__device__ inline float gelu_exact(float x) {
  return 0.5f * x * (1.f + erff(x * 0.70710678118654752f));
}

// ---------------- bf16 MFMA GEMM: C = act(A @ W^T [+ bias] [+ addC]) ----------------
// Round-6 proven 2-phase structure. A:[M,K], W:[N,K] bf16 row-major.
// BM=NBM*64, BN=NBN*64; WRxWC waves; wave owns (BM/WR)x(BN/WC).
// NEW (round 8):
//   STATS: epilogue accumulates per-row sum/sumsq of the fp32 outputs into
//          rs_out[row*2 +{0,1}] (shuffle-reduce over the 16 col-lanes -> 1 atomic
//          per row per wave). Requires M,N exact multiples of the tile.
//   LNA:   A operand is LayerNorm(h) computed ON THE FLY: reg-staged from fp32 h
//          (Af32) using per-row mu/rstd from rs_in, scale/bias from ln_sc/ln_bi.
//          LDS layout written is byte-identical to the DMA layout.

template <int WR, int WC, int NBM, int NBN, int ACT, int OUT_BF16, int ADDC, int BIAS,
          int HBF, int SWZ, int STATS, int LNA>
__global__ __launch_bounds__(WR * WC * 64) void gemm_mfma_kernel(
    const bf16* __restrict__ A, const bf16* __restrict__ W,
    const float* __restrict__ bias, const float* __restrict__ addC,
    void* __restrict__ Cout, bf16* __restrict__ out2,
    const float* __restrict__ Af32, const float* __restrict__ rs_in,
    const float* __restrict__ ln_sc, const float* __restrict__ ln_bi,
    float* __restrict__ rs_out,
    int M, int N, int K, int gx) {
  constexpr int THREADS = WR * WC * 64;
  constexpr int BM = NBM * 64;
  constexpr int BN = NBN * 64;
  constexpr int MR = BM / (WR * 16);   // m-frags per wave
  constexpr int NR = BN / (WC * 16);   // n-frags per wave
  constexpr int ITA = (BM * 4) / THREADS;  // A staging chunks/thread per tile
  constexpr int ITB = (BN * 4) / THREADS;
  __shared__ __align__(16) bf16 sA[2][BM * 32];
  __shared__ __align__(16) bf16 sB[2][BN * 32];
  const int tid = threadIdx.x;
  const int lane = tid & 63;
  const int wid = tid >> 6;
  const int wr = wid / WC, wc = wid % WC;

  int bidx, bidy;
  if (SWZ) {
    // chunked XCD map (nwg % 8 == 0): each XCD gets a contiguous chunk;
    // bidx (M) varies fastest within the chunk -> B-panel stays L2-resident.
    int nwg = gridDim.x;
    int bid = blockIdx.x;
    int l = (bid & 7) * (nwg >> 3) + (bid >> 3);
    bidx = l % gx;
    bidy = l / gx;
  } else {
    bidx = blockIdx.x;
    bidy = blockIdx.y;
  }
  const int bm = bidx * BM, bn = bidy * BN;

  f32x4 acc[MR][NR];
#pragma unroll
  for (int m = 0; m < MR; ++m)
#pragma unroll
    for (int n = 0; n < NR; ++n) acc[m][n] = (f32x4){0.f, 0.f, 0.f, 0.f};

  const int rbase = lane & 15;
  const int g = lane >> 4;
  const int kq = (tid & 3) << 3;    // per-thread k offset within 32-chunk

  int arow[ITA], brow[ITB];
#pragma unroll
  for (int i = 0; i < ITA; ++i) {
    int r0 = bm + ((i * THREADS + tid) >> 2);
    arow[i] = (r0 < M) ? r0 : (M - 1);
  }
#pragma unroll
  for (int i = 0; i < ITB; ++i) {
    int r0 = bn + ((i * THREADS + tid) >> 2);
    brow[i] = (r0 < N) ? r0 : (N - 1);
  }

  // per-row LN constants (LNA): computed once, rows fixed per thread
  float mu_i[ITA], rs_i[ITA];
  if constexpr (LNA) {
#pragma unroll
    for (int i = 0; i < ITA; ++i) {
      float s = rs_in[arow[i] * 2];
      float q = rs_in[arow[i] * 2 + 1];
      float mu = s * (1.f / (float)K);
      float var = q * (1.f / (float)K) - mu * mu;
      mu_i[i] = mu;
      rs_i[i] = rsqrtf(var + LN_EPS);
    }
  }

  auto stageA = [&](int buf, int k0) {
    if constexpr (LNA) {
#pragma unroll
      for (int i = 0; i < ITA; ++i) {
        const float* hp = Af32 + (size_t)arow[i] * K + k0 + kq;
        float4 u0 = *(const float4*)(hp);
        float4 u1 = *(const float4*)(hp + 4);
        float4 s0 = *(const float4*)(ln_sc + k0 + kq);
        float4 s1 = *(const float4*)(ln_sc + k0 + kq + 4);
        float4 b0 = *(const float4*)(ln_bi + k0 + kq);
        float4 b1 = *(const float4*)(ln_bi + k0 + kq + 4);
        float mu = mu_i[i], rs = rs_i[i];
        bf16 o[8];
        o[0] = __float2bfloat16((u0.x - mu) * rs * s0.x + b0.x);
        o[1] = __float2bfloat16((u0.y - mu) * rs * s0.y + b0.y);
        o[2] = __float2bfloat16((u0.z - mu) * rs * s0.z + b0.z);
        o[3] = __float2bfloat16((u0.w - mu) * rs * s0.w + b0.w);
        o[4] = __float2bfloat16((u1.x - mu) * rs * s1.x + b1.x);
        o[5] = __float2bfloat16((u1.y - mu) * rs * s1.y + b1.y);
        o[6] = __float2bfloat16((u1.z - mu) * rs * s1.z + b1.z);
        o[7] = __float2bfloat16((u1.w - mu) * rs * s1.w + b1.w);
        *(short8*)(&sA[buf][(i * THREADS + tid) * 8]) = *(const short8*)o;
      }
    } else {
#pragma unroll
      for (int i = 0; i < ITA; ++i)
        __builtin_amdgcn_global_load_lds(
            (const __attribute__((address_space(1))) void*)(A + (size_t)arow[i] * K + k0 + kq),
            (__attribute__((address_space(3))) void*)(&sA[buf][(i * THREADS + tid) * 8]), 16, 0, 0);
    }
  };
  auto stageB = [&](int buf, int k0) {
#pragma unroll
    for (int i = 0; i < ITB; ++i)
      __builtin_amdgcn_global_load_lds(
          (const __attribute__((address_space(1))) void*)(W + (size_t)brow[i] * K + k0 + kq),
          (__attribute__((address_space(3))) void*)(&sB[buf][(i * THREADS + tid) * 8]), 16, 0, 0);
  };

  const int NT = K >> 5;
  stageA(0, 0);
  stageB(0, 0);
  __syncthreads();               // drain prologue stage (vmcnt + lgkmcnt)

  int cur = 0;
  for (int t = 0; t < NT; ++t) {
    if (t + 1 < NT) { stageA(cur ^ 1, (t + 1) << 5); stageB(cur ^ 1, (t + 1) << 5); }

    short8 af[MR], bfrag[NR];
#pragma unroll
    for (int m = 0; m < MR; ++m)
      af[m] = *(const short8*)(&sA[cur][(wr * (BM / WR) + m * 16 + rbase) * 32 + g * 8]);
#pragma unroll
    for (int n = 0; n < NR; ++n)
      bfrag[n] = *(const short8*)(&sB[cur][(wc * (BN / WC) + n * 16 + rbase) * 32 + g * 8]);
#pragma unroll
    for (int m = 0; m < MR; ++m)
#pragma unroll
      for (int n = 0; n < NR; ++n)
        acc[m][n] = __builtin_amdgcn_mfma_f32_16x16x32_bf16(af[m], bfrag[n], acc[m][n], 0, 0, 0);

    __syncthreads();             // one barrier per K-step
    cur ^= 1;
  }

  // C/D frag mapping: col = lane&15, row = (lane>>4)*4 + reg   [m89-verified]
  const int rb = (lane >> 4) * 4;
  const int cb = lane & 15;
  float ps[MR][4], pq[MR][4];
  if constexpr (STATS) {
#pragma unroll
    for (int m = 0; m < MR; ++m)
#pragma unroll
      for (int r = 0; r < 4; ++r) { ps[m][r] = 0.f; pq[m][r] = 0.f; }
  }
#pragma unroll
  for (int m = 0; m < MR; ++m) {
#pragma unroll
    for (int n = 0; n < NR; ++n) {
      int col = bn + wc * (BN / WC) + n * 16 + cb;
      if (col >= N) continue;
      int row0 = bm + wr * (BM / WR) + m * 16 + rb;
#pragma unroll
      for (int r = 0; r < 4; ++r) {
        int row = row0 + r;
        if (row >= M) continue;
        float v = acc[m][n][r];
        if (BIAS) v += bias[col];
        if (ADDC) v += addC[(size_t)row * N + col];
        if (ACT == 1) v = fmaxf(v, 0.f);
        if (ACT == 2) v = gelu_exact(v);
        if (STATS) { ps[m][r] += v; pq[m][r] += v * v; }
        if (OUT_BF16)
          ((bf16*)Cout)[(size_t)row * N + col] = __float2bfloat16(v);
        else
          ((float*)Cout)[(size_t)row * N + col] = v;
        if (HBF)
          out2[(size_t)row * N + col] = __float2bfloat16(v);
      }
    }
  }
  if constexpr (STATS) {
    // reduce each (m,r)'s partial across the 16 col-lanes, then one atomic/row/wave
#pragma unroll
    for (int m = 0; m < MR; ++m) {
#pragma unroll
      for (int r = 0; r < 4; ++r) {
        float s = ps[m][r], q = pq[m][r];
#pragma unroll
        for (int o = 1; o < 16; o <<= 1) { s += __shfl_xor(s, o); q += __shfl_xor(q, o); }
        if ((lane & 15) == 0) {
          int row = bm + wr * (BM / WR) + m * 16 + rb + r;
          atomicAdd(&rs_out[row * 2], s);
          atomicAdd(&rs_out[row * 2 + 1], q);
        }
      }
    }
  }
}

template <int WR, int WC, int NBM, int NBN, int ACT, int OUT_BF16, int ADDC, int BIAS,
          int HBF, int STATS, int LNA>
static void launch_mfma(const bf16* A, const bf16* W, const float* bias,
                        const float* addC, void* C, bf16* out2,
                        const float* Af32, const float* rs_in,
                        const float* ln_sc, const float* ln_bi, float* rs_out,
                        int M, int N, int K, hipStream_t stream) {
  dim3 grid(M / (NBM * 64), (N + NBN * 64 - 1) / (NBN * 64));
  gemm_mfma_kernel<WR, WC, NBM, NBN, ACT, OUT_BF16, ADDC, BIAS, HBF, 0, STATS, LNA>
      <<<grid, WR * WC * 64, 0, stream>>>(A, W, bias, addC, C, out2,
                                          Af32, rs_in, ln_sc, ln_bi, rs_out, M, N, K, 0);
}

// ---------------- launch ----------------

#define MB (1024u * 1024u)

extern "C" void kernel_launch(void* const* d_in, const int* in_sizes, int n_in,
                              void* d_out, int out_size, void* d_ws, size_t ws_size,
                              hipStream_t stream) {
  const int*   node_indices = (const int*)d_in[0];
  const int*   edge_index   = (const int*)d_in[1];
  const float* edge_weight  = (const float*)d_in[2];
  const float* cache        = (const float*)d_in[3];
  const float* w_root       = (const float*)d_in[4];
  const float* w_neigh      = (const float*)d_in[5];
  const float* w_post       = (const float*)d_in[6];
  const float* b_post       = (const float*)d_in[7];
  const float* fallback     = (const float*)d_in[8];
  const float* ln_in_scale  = (const float*)d_in[9];
  const float* ln_in_bias   = (const float*)d_in[10];
  const float* w_in         = (const float*)d_in[11];
  const float* rb_ln_scale  = (const float*)d_in[12];
  const float* rb_ln_bias   = (const float*)d_in[13];
  const float* rb_fc1       = (const float*)d_in[14];
  const float* rb_fc2       = (const float*)d_in[15];
  const float* w_bil        = (const float*)d_in[16];
  const float* gene         = (const float*)d_in[17];
  float* out = (float*)d_out;

  char* w = (char*)d_ws;
  // --- region A (0..24 MB): graph-stage buffers, dead after gather_ln; ymid aliases ---
  bf16*  compact2 = (bf16*)(w + 0 * MB);   // 4 MB
  bf16*  tmpc     = (bf16*)(w + 4 * MB);   // 2 MB
  float* embc     = (float*)(w + 6 * MB);  // 4 MB
  int*   el_src   = (int*)  (w + 10 * MB); // 2 MB
  float* el_w     = (float*)(w + 12 * MB); // 2 MB
  int*   flags    = (int*)  (w + 14 * MB);
  int*   slot     = (int*)  (w + 14 * MB + 80 * 1024);
  int*   uniq     = (int*)  (w + 14 * MB + 160 * 1024);
  int*   cursor   = (int*)  (w + 14 * MB + 180 * 1024);
  int*   nuniq    = (int*)  (w + 14 * MB + 200 * 1024);
  bf16*  ymid     = (bf16*) (w + 0 * MB);  // 16 MB (phase-4 only, region A dead)
  // --- region B (24 MB..): activations + bf16 weights ---
  bf16*  pertln  = (bf16*) (w + 24 * MB);
  float* h       = (float*)(w + 26 * MB);
  bf16*  h_bf    = (bf16*) (w + 38 * MB);
  bf16*  blin    = (bf16*) (w + 42 * MB);
  bf16*  w_in_bf = (bf16*) (w + 55 * MB);
  bf16*  fc1_bf  = (bf16*) (w + 56 * MB);
  bf16*  fc2_bf  = (bf16*) (w + 68 * MB);
  bf16*  wbil_bf = (bf16*) (w + 80 * MB);
  bf16*  gene_bf = (bf16*) (w + 82 * MB);
  bf16*  wrn_bf  = (bf16*) (w + 90 * MB);
  bf16*  wpost_bf= (bf16*) (w + 91 * MB);
  float* rowstat = (float*)(w + 92 * MB);  // 6 layers x 4096 x {sum, sumsq} = 192 KB

  // 0) all weight conversions in ONE kernel
  convert_weights_kernel<<<(CONV_TOT + 255) / 256, 256, 0, stream>>>(
      w_in, rb_fc1, rb_fc2, w_bil, gene, w_post, w_root, w_neigh,
      w_in_bf, fc1_bf, fc2_bf, wbil_bf, gene_bf, wpost_bf, wrn_bf);

  // 1) compact-slot construction + bucketed edge lists + gather-accumulate (bf16 out)
  init_meta_kernel<<<(N_NODES + 255) / 256, 256, 0, stream>>>(flags, cursor, nuniq, rowstat);
  mark_needed_kernel<<<(BATCH + 255) / 256, 256, 0, stream>>>(node_indices, flags);
  assign_slots_kernel<<<(N_NODES + 255) / 256, 256, 0, stream>>>(flags, slot, uniq, nuniq);
  fill_edges_kernel<<<(N_EDGES + 255) / 256, 256, 0, stream>>>(
      edge_index, edge_weight, flags, slot, cursor, el_src, el_w);
  gather_nodes_kernel<<<BATCH, 256, 0, stream>>>(
      cache, uniq, cursor, nuniq, el_src, el_w, compact2);

  // 2) compact graph tail (bf16 MFMA, 64x64): relu([cache|agg]@[wr|wn]^T) @ w_post^T + b
  launch_mfma<2, 2, 1, 1, 1, 1, 0, 0, 0, 0, 0>(
      compact2, wrn_bf, nullptr, nullptr, tmpc, nullptr,
      nullptr, nullptr, nullptr, nullptr, nullptr, BATCH, GNN_D, 2 * GNN_D, stream);
  launch_mfma<2, 2, 1, 1, 0, 0, 0, 1, 0, 0, 0>(
      tmpc, wpost_bf, b_post, nullptr, embc, nullptr,
      nullptr, nullptr, nullptr, nullptr, nullptr, BATCH, GNN_D, GNN_D, stream);

  // 3) gather + input LN (bf16 out), input proj (64x64) -> h fp32 + rowstat[0]
  gather_ln_kernel<<<BATCH, 256, 0, stream>>>(embc, slot, fallback, node_indices,
                                              ln_in_scale, ln_in_bias, pertln);
  launch_mfma<2, 2, 1, 1, 0, 0, 0, 0, 0, 1, 0>(
      pertln, w_in_bf, nullptr, nullptr, h, nullptr,
      nullptr, nullptr, nullptr, nullptr, rowstat, BATCH, H_D, GNN_D, stream);

  // 4) residual blocks: fc1 = gelu(LN(h) @ fc1^T), LN fused into A-staging (LNA);
  //    fc2 = ymid @ fc2^T + h, emitting next layer's row stats (STATS)
  for (int i = 0; i < L_N; ++i) {
    launch_mfma<2, 2, 2, 2, 2, 1, 0, 0, 0, 0, 1>(
        nullptr, fc1_bf + (size_t)i * MID_D * H_D, nullptr, nullptr, ymid, nullptr,
        h, rowstat + (size_t)i * BATCH * 2,
        rb_ln_scale + (size_t)i * H_D, rb_ln_bias + (size_t)i * H_D, nullptr,
        BATCH, MID_D, H_D, stream);
    if (i < L_N - 1)
      launch_mfma<2, 2, 1, 1, 0, 0, 1, 0, 0, 1, 0>(
          ymid, fc2_bf + (size_t)i * H_D * MID_D, nullptr, h, h, nullptr,
          nullptr, nullptr, nullptr, nullptr, rowstat + (size_t)(i + 1) * BATCH * 2,
          BATCH, H_D, MID_D, stream);
    else  // last layer: no stats; also emit bf16 h for the bilinear head
      launch_mfma<2, 2, 1, 1, 0, 0, 1, 0, 1, 0, 0>(
          ymid, fc2_bf + (size_t)i * H_D * MID_D, nullptr, h, h, h_bf,
          nullptr, nullptr, nullptr, nullptr, nullptr,
          BATCH, H_D, MID_D, stream);
  }

  // 5) bilinear head (64x128, bf16 out) + gene einsum (8-wave 256x256, fp32 out,
  //    chunked-XCD 1D grid: bidx fast within each XCD chunk)
  launch_mfma<2, 2, 1, 2, 0, 1, 0, 0, 0, 0, 0>(
      h_bf, wbil_bf, nullptr, nullptr, blin, nullptr,
      nullptr, nullptr, nullptr, nullptr, nullptr, BATCH, C_N * R_D, H_D, stream);
  {
    int gx = (BATCH * C_N) / 256;            // 48
    int gy = (G_N + 255) / 256;              // 26
    int nwg = gx * gy;                       // 1248 (divisible by 8)
    gemm_mfma_kernel<2, 4, 4, 4, 0, 0, 0, 0, 0, 1, 0, 0><<<nwg, 512, 0, stream>>>(
        blin, gene_bf, nullptr, nullptr, out, nullptr,
        nullptr, nullptr, nullptr, nullptr, nullptr, BATCH * C_N, G_N, R_D, gx);
  }
}

// Round 10
// 651.725 us; speedup vs baseline: 1.0173x; 1.0173x over previous
//
#include <hip/hip_runtime.h>
#include <hip/hip_bf16.h>

#define N_NODES 19000
#define N_EDGES 600000
#define BATCH   4096
#define GNN_D   256
#define H_D     512
#define MID_D   2048
#define L_N     6
#define C_N     3
#define R_D     512
#define G_N     6640
#define LN_EPS  1e-5f
#define MAXDEG  128

typedef __attribute__((ext_vector_type(8))) short short8;
typedef __attribute__((ext_vector_type(4))) float f32x4;
typedef __hip_bfloat16 bf16;

// ---------------- merged weight conversion (7 dsts, 1 launch) ----------------
#define SEG0 32768                    // w_in   512*256/4
#define SEG1 (SEG0 + 1572864)         // fc1    6*2048*512/4
#define SEG2 (SEG1 + 1572864)         // fc2
#define SEG3 (SEG2 + 196608)          // wbil   3*512*512/4
#define SEG4 (SEG3 + 849920)          // gene   6640*512/4
#define SEG5 (SEG4 + 16384)           // wpost  256*256/4
#define SEG6 (SEG5 + 32768)           // wrn    256*512/4
#define CONV_TOT SEG6

__global__ void convert_weights_kernel(
    const float* __restrict__ w_in, const float* __restrict__ fc1,
    const float* __restrict__ fc2, const float* __restrict__ wbil,
    const float* __restrict__ gene, const float* __restrict__ wpost,
    const float* __restrict__ wroot, const float* __restrict__ wneigh,
    bf16* __restrict__ o_win, bf16* __restrict__ o_fc1, bf16* __restrict__ o_fc2,
    bf16* __restrict__ o_wbil, bf16* __restrict__ o_gene, bf16* __restrict__ o_wpost,
    bf16* __restrict__ o_wrn) {
  int i = blockIdx.x * blockDim.x + threadIdx.x;
  if (i >= CONV_TOT) return;
  const float* src;
  bf16* dst;
  if (i < SEG0)      { src = w_in  + (size_t)i * 4;            dst = o_win  + (size_t)i * 4; }
  else if (i < SEG1) { size_t j = i - SEG0; src = fc1  + j * 4; dst = o_fc1  + j * 4; }
  else if (i < SEG2) { size_t j = i - SEG1; src = fc2  + j * 4; dst = o_fc2  + j * 4; }
  else if (i < SEG3) { size_t j = i - SEG2; src = wbil + j * 4; dst = o_wbil + j * 4; }
  else if (i < SEG4) { size_t j = i - SEG3; src = gene + j * 4; dst = o_gene + j * 4; }
  else if (i < SEG5) { size_t j = i - SEG4; src = wpost+ j * 4; dst = o_wpost+ j * 4; }
  else {  // wrn: [256][512] = [w_root | w_neigh]
    int j = i - SEG5;
    int base = j * 4;
    int n = base >> 9;
    int k = base & 511;
    src = (k < GNN_D) ? (wroot + (size_t)n * GNN_D + k)
                      : (wneigh + (size_t)n * GNN_D + (k - GNN_D));
    dst = o_wrn + base;
  }
  float4 v = *(const float4*)src;
  dst[0] = __float2bfloat16(v.x);
  dst[1] = __float2bfloat16(v.y);
  dst[2] = __float2bfloat16(v.z);
  dst[3] = __float2bfloat16(v.w);
}

// ---------------- graph compaction kernels (unchanged, proven) ----------------

__global__ void init_meta_kernel(int* __restrict__ flags, int* __restrict__ cursor,
                                 int* __restrict__ nuniq) {
  int i = blockIdx.x * blockDim.x + threadIdx.x;
  if (i < N_NODES) flags[i] = 0;
  if (i < BATCH) cursor[i] = 0;
  if (i == 0) *nuniq = 0;
}

__global__ void mark_needed_kernel(const int* __restrict__ idx, int* __restrict__ flags) {
  int i = blockIdx.x * blockDim.x + threadIdx.x;
  if (i < BATCH) {
    int id = idx[i];
    if (id >= 0) flags[id] = 1;
  }
}

__global__ void assign_slots_kernel(const int* __restrict__ flags, int* __restrict__ slot,
                                    int* __restrict__ uniq, int* __restrict__ nuniq) {
  int i = blockIdx.x * blockDim.x + threadIdx.x;
  if (i >= N_NODES) return;
  if (flags[i]) {
    int s = atomicAdd(nuniq, 1);
    slot[i] = s;
    uniq[s] = i;
  }
}

__global__ __launch_bounds__(256) void fill_edges_kernel(
    const int* __restrict__ ei, const float* __restrict__ ew,
    const int* __restrict__ flags, const int* __restrict__ slot,
    int* __restrict__ cursor, int* __restrict__ el_src, float* __restrict__ el_w) {
  int e = blockIdx.x * blockDim.x + threadIdx.x;
  if (e >= N_EDGES) return;
  int dst = ei[N_EDGES + e];
  if (!flags[dst]) return;
  int s = slot[dst];
  int p = atomicAdd(&cursor[s], 1);
  if (p < MAXDEG) {
    el_src[s * MAXDEG + p] = ei[e];
    el_w[s * MAXDEG + p] = ew[e];
  }
}

__global__ __launch_bounds__(256) void gather_nodes_kernel(
    const float* __restrict__ cache, const int* __restrict__ uniq,
    const int* __restrict__ cursor, const int* __restrict__ nuniq,
    const int* __restrict__ el_src, const float* __restrict__ el_w,
    bf16* __restrict__ compact2) {
  int s = blockIdx.x, t = threadIdx.x;
  bf16* row = compact2 + (size_t)s * (2 * GNN_D);
  if (s >= *nuniq) {
    row[t] = __float2bfloat16(0.f);
    row[GNN_D + t] = __float2bfloat16(0.f);
    return;
  }
  row[t] = __float2bfloat16(cache[(size_t)uniq[s] * GNN_D + t]);
  int deg = cursor[s];
  deg = (deg < MAXDEG) ? deg : MAXDEG;
  float acc = 0.f;
  for (int e = 0; e < deg; ++e) {
    int src = el_src[s * MAXDEG + e];
    float w = el_w[s * MAXDEG + e];
    acc += cache[(size_t)src * GNN_D + t] * w;
  }
  row[GNN_D + t] = __float2bfloat16(acc);
}

__global__ __launch_bounds__(256) void gather_ln_kernel(
    const float* __restrict__ embc, const int* __restrict__ slot,
    const float* __restrict__ fallback, const int* __restrict__ idx,
    const float* __restrict__ scale, const float* __restrict__ bias,
    bf16* __restrict__ out) {
  int b = blockIdx.x, t = threadIdx.x;
  int id = idx[b];
  float v = (id >= 0) ? embc[(size_t)slot[id] * GNN_D + t] : fallback[t];
  float s = v, q = v * v;
#pragma unroll
  for (int o = 32; o > 0; o >>= 1) { s += __shfl_down(s, o); q += __shfl_down(q, o); }
  __shared__ float ls[4], lq[4];
  int wv = t >> 6, ln = t & 63;
  if (ln == 0) { ls[wv] = s; lq[wv] = q; }
  __syncthreads();
  s = ls[0] + ls[1] + ls[2] + ls[3];
  q = lq[0] + lq[1] + lq[2] + lq[3];
  float mu = s * (1.f / GNN_D);
  float var = q * (1.f / GNN_D) - mu * mu;
  float r = rsqrtf(var + LN_EPS);
  out[(size_t)b * GNN_D + t] = __float2bfloat16((v - mu) * r * scale[t] + bias[t]);
}

__global__ __launch_bounds__(256) void ln512_kernel(
    const float* __restrict__ x, const float* __restrict__ scale,
    const float* __restrict__ bias, bf16* __restrict__ out) {
  int b = blockIdx.x, t = threadIdx.x;
  const float* xr = x + (size_t)b * H_D;
  float v0 = xr[t];
  float v1 = xr[256 + t];
  float s = v0 + v1, q = v0 * v0 + v1 * v1;
#pragma unroll
  for (int o = 32; o > 0; o >>= 1) { s += __shfl_down(s, o); q += __shfl_down(q, o); }
  __shared__ float ls[4], lq[4];
  int wv = t >> 6, ln = t & 63;
  if (ln == 0) { ls[wv] = s; lq[wv] = q; }
  __syncthreads();
  s = ls[0] + ls[1] + ls[2] + ls[3];
  q = lq[0] + lq[1] + lq[2] + lq[3];
  float mu = s * (1.f / H_D);
  float var = q * (1.f / H_D) - mu * mu;
  float r = rsqrtf(var + LN_EPS);
  bf16* orow = out + (size_t)b * H_D;
  orow[t]       = __float2bfloat16((v0 - mu) * r * scale[t]       + bias[t]);
  orow[256 + t] = __float2bfloat16((v1 - mu) * r * scale[256 + t] + bias[256 + t]);
}

__device__ inline float gelu_exact(float x) {
  return 0.5f * x * (1.f + erff(x * 0.70710678118654752f));
}

// ---------------- bf16 MFMA GEMM: C = act(A @ W^T [+ bias] [+ addC]) ----------------
// Round-6 proven 2-phase structure + KSTEP parameter. A:[M,K], W:[N,K] bf16 row-major.
// BM=NBM*64, BN=NBN*64; WRxWC waves; wave owns (BM/WR)x(BN/WC).
// KSTEP=64 halves barrier/drain count for small tiles (LDS stays 2-buf; occupancy kept).
// 2-phase: issue next-slab global_load_lds into buf^1 BEFORE ds_read+MFMA of buf;
// single __syncthreads (vmcnt+lgkm drain) per K-slab.

template <int WR, int WC, int NBM, int NBN, int KSTEP, int ACT, int OUT_BF16, int ADDC,
          int BIAS, int HBF, int SWZ>
__global__ __launch_bounds__(WR * WC * 64) void gemm_mfma_kernel(
    const bf16* __restrict__ A, const bf16* __restrict__ W,
    const float* __restrict__ bias, const float* __restrict__ addC,
    void* __restrict__ Cout, bf16* __restrict__ out2,
    int M, int N, int K, int gx) {
  constexpr int THREADS = WR * WC * 64;
  constexpr int BM = NBM * 64;
  constexpr int BN = NBN * 64;
  constexpr int MR = BM / (WR * 16);       // m-frags per wave
  constexpr int NR = BN / (WC * 16);       // n-frags per wave
  constexpr int KC = KSTEP / 8;            // 16B chunks per row per slab
  constexpr int ITA = BM * KC / THREADS;   // A staging chunks/thread per slab
  constexpr int ITB = BN * KC / THREADS;
  constexpr int KH = KSTEP / 32;           // MFMA k-halves per slab
  __shared__ __align__(16) bf16 sA[2][BM * KSTEP];
  __shared__ __align__(16) bf16 sB[2][BN * KSTEP];
  const int tid = threadIdx.x;
  const int lane = tid & 63;
  const int wid = tid >> 6;
  const int wr = wid / WC, wc = wid % WC;

  int bidx, bidy;
  if (SWZ) {
    // chunked XCD map (nwg % 8 == 0): each XCD gets a contiguous chunk;
    // bidx (M) varies fastest within the chunk -> B-panel stays L2-resident.
    int nwg = gridDim.x;
    int bid = blockIdx.x;
    int l = (bid & 7) * (nwg >> 3) + (bid >> 3);
    bidx = l % gx;
    bidy = l / gx;
  } else {
    bidx = blockIdx.x;
    bidy = blockIdx.y;
  }
  const int bm = bidx * BM, bn = bidy * BN;

  f32x4 acc[MR][NR];
#pragma unroll
  for (int m = 0; m < MR; ++m)
#pragma unroll
    for (int n = 0; n < NR; ++n) acc[m][n] = (f32x4){0.f, 0.f, 0.f, 0.f};

  const int rbase = lane & 15;
  const int g = lane >> 4;
  const int kq = (tid & (KC - 1)) << 3;    // per-thread k elem offset within slab

  int arow[ITA], brow[ITB];
#pragma unroll
  for (int i = 0; i < ITA; ++i) {
    int r0 = bm + (i * THREADS + tid) / KC;
    arow[i] = (r0 < M) ? r0 : (M - 1);
  }
#pragma unroll
  for (int i = 0; i < ITB; ++i) {
    int r0 = bn + (i * THREADS + tid) / KC;
    brow[i] = (r0 < N) ? r0 : (N - 1);
  }

  auto stage = [&](int buf, int k0) {
#pragma unroll
    for (int i = 0; i < ITA; ++i)
      __builtin_amdgcn_global_load_lds(
          (const __attribute__((address_space(1))) void*)(A + (size_t)arow[i] * K + k0 + kq),
          (__attribute__((address_space(3))) void*)(&sA[buf][(i * THREADS + tid) * 8]), 16, 0, 0);
#pragma unroll
    for (int i = 0; i < ITB; ++i)
      __builtin_amdgcn_global_load_lds(
          (const __attribute__((address_space(1))) void*)(W + (size_t)brow[i] * K + k0 + kq),
          (__attribute__((address_space(3))) void*)(&sB[buf][(i * THREADS + tid) * 8]), 16, 0, 0);
  };

  const int NT = K / KSTEP;
  stage(0, 0);
  __syncthreads();               // drain prologue stage

  int cur = 0;
  for (int t = 0; t < NT; ++t) {
    if (t + 1 < NT) stage(cur ^ 1, (t + 1) * KSTEP);   // issue next slab early

#pragma unroll
    for (int kh = 0; kh < KH; ++kh) {
      short8 af[MR], bfrag[NR];
#pragma unroll
      for (int m = 0; m < MR; ++m)
        af[m] = *(const short8*)(
            &sA[cur][(wr * (BM / WR) + m * 16 + rbase) * KSTEP + kh * 32 + g * 8]);
#pragma unroll
      for (int n = 0; n < NR; ++n)
        bfrag[n] = *(const short8*)(
            &sB[cur][(wc * (BN / WC) + n * 16 + rbase) * KSTEP + kh * 32 + g * 8]);
#pragma unroll
      for (int m = 0; m < MR; ++m)
#pragma unroll
        for (int n = 0; n < NR; ++n)
          acc[m][n] = __builtin_amdgcn_mfma_f32_16x16x32_bf16(af[m], bfrag[n], acc[m][n], 0, 0, 0);
    }

    __syncthreads();             // one barrier per K-slab
    cur ^= 1;
  }

  // C/D frag mapping: col = lane&15, row = (lane>>4)*4 + reg   [m89-verified]
  const int rb = (lane >> 4) * 4;
  const int cb = lane & 15;
#pragma unroll
  for (int m = 0; m < MR; ++m) {
#pragma unroll
    for (int n = 0; n < NR; ++n) {
      int col = bn + wc * (BN / WC) + n * 16 + cb;
      if (col >= N) continue;
      int row0 = bm + wr * (BM / WR) + m * 16 + rb;
#pragma unroll
      for (int r = 0; r < 4; ++r) {
        int row = row0 + r;
        if (row >= M) continue;
        float v = acc[m][n][r];
        if (BIAS) v += bias[col];
        if (ADDC) v += addC[(size_t)row * N + col];
        if (ACT == 1) v = fmaxf(v, 0.f);
        if (ACT == 2) v = gelu_exact(v);
        if (OUT_BF16)
          ((bf16*)Cout)[(size_t)row * N + col] = __float2bfloat16(v);
        else
          ((float*)Cout)[(size_t)row * N + col] = v;
        if (HBF)
          out2[(size_t)row * N + col] = __float2bfloat16(v);
      }
    }
  }
}

template <int WR, int WC, int NBM, int NBN, int KSTEP, int ACT, int OUT_BF16, int ADDC,
          int BIAS, int HBF>
static void launch_mfma(const bf16* A, const bf16* W, const float* bias,
                        const float* addC, void* C, bf16* out2,
                        int M, int N, int K, hipStream_t stream) {
  dim3 grid(M / (NBM * 64), (N + NBN * 64 - 1) / (NBN * 64));
  gemm_mfma_kernel<WR, WC, NBM, NBN, KSTEP, ACT, OUT_BF16, ADDC, BIAS, HBF, 0>
      <<<grid, WR * WC * 64, 0, stream>>>(A, W, bias, addC, C, out2, M, N, K, 0);
}

// ---------------- launch ----------------

#define MB (1024u * 1024u)

extern "C" void kernel_launch(void* const* d_in, const int* in_sizes, int n_in,
                              void* d_out, int out_size, void* d_ws, size_t ws_size,
                              hipStream_t stream) {
  const int*   node_indices = (const int*)d_in[0];
  const int*   edge_index   = (const int*)d_in[1];
  const float* edge_weight  = (const float*)d_in[2];
  const float* cache        = (const float*)d_in[3];
  const float* w_root       = (const float*)d_in[4];
  const float* w_neigh      = (const float*)d_in[5];
  const float* w_post       = (const float*)d_in[6];
  const float* b_post       = (const float*)d_in[7];
  const float* fallback     = (const float*)d_in[8];
  const float* ln_in_scale  = (const float*)d_in[9];
  const float* ln_in_bias   = (const float*)d_in[10];
  const float* w_in         = (const float*)d_in[11];
  const float* rb_ln_scale  = (const float*)d_in[12];
  const float* rb_ln_bias   = (const float*)d_in[13];
  const float* rb_fc1       = (const float*)d_in[14];
  const float* rb_fc2       = (const float*)d_in[15];
  const float* w_bil        = (const float*)d_in[16];
  const float* gene         = (const float*)d_in[17];
  float* out = (float*)d_out;

  char* w = (char*)d_ws;
  // --- region A (0..24 MB): graph-stage buffers, dead after gather_ln; ymid aliases ---
  bf16*  compact2 = (bf16*)(w + 0 * MB);   // 4 MB
  bf16*  tmpc     = (bf16*)(w + 4 * MB);   // 2 MB
  float* embc     = (float*)(w + 6 * MB);  // 4 MB
  int*   el_src   = (int*)  (w + 10 * MB); // 2 MB
  float* el_w     = (float*)(w + 12 * MB); // 2 MB
  int*   flags    = (int*)  (w + 14 * MB);
  int*   slot     = (int*)  (w + 14 * MB + 80 * 1024);
  int*   uniq     = (int*)  (w + 14 * MB + 160 * 1024);
  int*   cursor   = (int*)  (w + 14 * MB + 180 * 1024);
  int*   nuniq    = (int*)  (w + 14 * MB + 200 * 1024);
  bf16*  ymid     = (bf16*) (w + 0 * MB);  // 16 MB (phase-4 only, region A dead)
  // --- region B (24 MB..): activations + bf16 weights ---
  bf16*  pertln  = (bf16*) (w + 24 * MB);
  float* h       = (float*)(w + 26 * MB);
  bf16*  yln     = (bf16*) (w + 34 * MB);
  bf16*  h_bf    = (bf16*) (w + 38 * MB);
  bf16*  blin    = (bf16*) (w + 42 * MB);
  bf16*  w_in_bf = (bf16*) (w + 55 * MB);
  bf16*  fc1_bf  = (bf16*) (w + 56 * MB);
  bf16*  fc2_bf  = (bf16*) (w + 68 * MB);
  bf16*  wbil_bf = (bf16*) (w + 80 * MB);
  bf16*  gene_bf = (bf16*) (w + 82 * MB);
  bf16*  wrn_bf  = (bf16*) (w + 90 * MB);
  bf16*  wpost_bf= (bf16*) (w + 91 * MB);

  // 0) all weight conversions in ONE kernel
  convert_weights_kernel<<<(CONV_TOT + 255) / 256, 256, 0, stream>>>(
      w_in, rb_fc1, rb_fc2, w_bil, gene, w_post, w_root, w_neigh,
      w_in_bf, fc1_bf, fc2_bf, wbil_bf, gene_bf, wpost_bf, wrn_bf);

  // 1) compact-slot construction + bucketed edge lists + gather-accumulate (bf16 out)
  init_meta_kernel<<<(N_NODES + 255) / 256, 256, 0, stream>>>(flags, cursor, nuniq);
  mark_needed_kernel<<<(BATCH + 255) / 256, 256, 0, stream>>>(node_indices, flags);
  assign_slots_kernel<<<(N_NODES + 255) / 256, 256, 0, stream>>>(flags, slot, uniq, nuniq);
  fill_edges_kernel<<<(N_EDGES + 255) / 256, 256, 0, stream>>>(
      edge_index, edge_weight, flags, slot, cursor, el_src, el_w);
  gather_nodes_kernel<<<BATCH, 256, 0, stream>>>(
      cache, uniq, cursor, nuniq, el_src, el_w, compact2);

  // 2) compact graph tail (bf16 MFMA, 64x64, KSTEP=64):
  //    relu([cache|agg]@[wr|wn]^T) @ w_post^T + b
  launch_mfma<2, 2, 1, 1, 64, 1, 1, 0, 0, 0>(compact2, wrn_bf, nullptr, nullptr, tmpc,
                                             nullptr, BATCH, GNN_D, 2 * GNN_D, stream);
  launch_mfma<2, 2, 1, 1, 64, 0, 0, 0, 1, 0>(tmpc, wpost_bf, b_post, nullptr, embc,
                                             nullptr, BATCH, GNN_D, GNN_D, stream);

  // 3) gather + input LN (bf16 out), input proj (64x64, KSTEP=64) -> h fp32
  gather_ln_kernel<<<BATCH, 256, 0, stream>>>(embc, slot, fallback, node_indices,
                                              ln_in_scale, ln_in_bias, pertln);
  launch_mfma<2, 2, 1, 1, 64, 0, 0, 0, 0, 0>(pertln, w_in_bf, nullptr, nullptr, h,
                                             nullptr, BATCH, H_D, GNN_D, stream);

  // 4) residual blocks: LN -> fc1(gelu, bf16, 128x128, KSTEP=32)
  //                        -> fc2(+h, fp32, 64x64, KSTEP=64)
  for (int i = 0; i < L_N; ++i) {
    ln512_kernel<<<BATCH, 256, 0, stream>>>(h, rb_ln_scale + (size_t)i * H_D,
                                            rb_ln_bias + (size_t)i * H_D, yln);
    launch_mfma<2, 2, 2, 2, 32, 2, 1, 0, 0, 0>(yln, fc1_bf + (size_t)i * MID_D * H_D,
                                               nullptr, nullptr, ymid, nullptr,
                                               BATCH, MID_D, H_D, stream);
    if (i < L_N - 1)
      launch_mfma<2, 2, 1, 1, 64, 0, 0, 1, 0, 0>(ymid, fc2_bf + (size_t)i * H_D * MID_D,
                                                 nullptr, h, h, nullptr,
                                                 BATCH, H_D, MID_D, stream);
    else  // last layer: also emit bf16 h for the bilinear head
      launch_mfma<2, 2, 1, 1, 64, 0, 0, 1, 0, 1>(ymid, fc2_bf + (size_t)i * H_D * MID_D,
                                                 nullptr, h, h, h_bf,
                                                 BATCH, H_D, MID_D, stream);
  }

  // 5) bilinear head (64x128, KSTEP=64, bf16 out) + gene einsum (8-wave 256x256,
  //    KSTEP=32, fp32 out, chunked-XCD 1D grid)
  launch_mfma<2, 2, 1, 2, 64, 0, 1, 0, 0, 0>(h_bf, wbil_bf, nullptr, nullptr, blin,
                                             nullptr, BATCH, C_N * R_D, H_D, stream);
  {
    int gx = (BATCH * C_N) / 256;            // 48
    int gy = (G_N + 255) / 256;              // 26
    int nwg = gx * gy;                       // 1248 (divisible by 8)
    gemm_mfma_kernel<2, 4, 4, 4, 32, 0, 0, 0, 0, 0, 1><<<nwg, 512, 0, stream>>>(
        blin, gene_bf, nullptr, nullptr, out, nullptr, BATCH * C_N, G_N, R_D, gx);
  }
}

// Round 11
// 627.731 us; speedup vs baseline: 1.0561x; 1.0382x over previous
//
#include <hip/hip_runtime.h>
#include <hip/hip_bf16.h>

#define N_NODES 19000
#define N_EDGES 600000
#define BATCH   4096
#define GNN_D   256
#define H_D     512
#define MID_D   2048
#define L_N     6
#define C_N     3
#define R_D     512
#define G_N     6640
#define LN_EPS  1e-5f
#define MAXDEG  128

typedef __attribute__((ext_vector_type(8))) short short8;
typedef __attribute__((ext_vector_type(4))) float f32x4;
typedef __hip_bfloat16 bf16;

// ---------------- merged weight conversion (7 dsts, 1 launch) ----------------
#define SEG0 32768                    // w_in   512*256/4
#define SEG1 (SEG0 + 1572864)         // fc1    6*2048*512/4
#define SEG2 (SEG1 + 1572864)         // fc2
#define SEG3 (SEG2 + 196608)          // wbil   3*512*512/4
#define SEG4 (SEG3 + 849920)          // gene   6640*512/4
#define SEG5 (SEG4 + 16384)           // wpost  256*256/4
#define SEG6 (SEG5 + 32768)           // wrn    256*512/4
#define CONV_TOT SEG6

__global__ void convert_weights_kernel(
    const float* __restrict__ w_in, const float* __restrict__ fc1,
    const float* __restrict__ fc2, const float* __restrict__ wbil,
    const float* __restrict__ gene, const float* __restrict__ wpost,
    const float* __restrict__ wroot, const float* __restrict__ wneigh,
    bf16* __restrict__ o_win, bf16* __restrict__ o_fc1, bf16* __restrict__ o_fc2,
    bf16* __restrict__ o_wbil, bf16* __restrict__ o_gene, bf16* __restrict__ o_wpost,
    bf16* __restrict__ o_wrn) {
  int i = blockIdx.x * blockDim.x + threadIdx.x;
  if (i >= CONV_TOT) return;
  const float* src;
  bf16* dst;
  if (i < SEG0)      { src = w_in  + (size_t)i * 4;            dst = o_win  + (size_t)i * 4; }
  else if (i < SEG1) { size_t j = i - SEG0; src = fc1  + j * 4; dst = o_fc1  + j * 4; }
  else if (i < SEG2) { size_t j = i - SEG1; src = fc2  + j * 4; dst = o_fc2  + j * 4; }
  else if (i < SEG3) { size_t j = i - SEG2; src = wbil + j * 4; dst = o_wbil + j * 4; }
  else if (i < SEG4) { size_t j = i - SEG3; src = gene + j * 4; dst = o_gene + j * 4; }
  else if (i < SEG5) { size_t j = i - SEG4; src = wpost+ j * 4; dst = o_wpost+ j * 4; }
  else {  // wrn: [256][512] = [w_root | w_neigh]
    int j = i - SEG5;
    int base = j * 4;
    int n = base >> 9;
    int k = base & 511;
    src = (k < GNN_D) ? (wroot + (size_t)n * GNN_D + k)
                      : (wneigh + (size_t)n * GNN_D + (k - GNN_D));
    dst = o_wrn + base;
  }
  float4 v = *(const float4*)src;
  dst[0] = __float2bfloat16(v.x);
  dst[1] = __float2bfloat16(v.y);
  dst[2] = __float2bfloat16(v.z);
  dst[3] = __float2bfloat16(v.w);
}

// ---------------- graph compaction kernels (unchanged, proven) ----------------

__global__ void init_meta_kernel(int* __restrict__ flags, int* __restrict__ cursor,
                                 int* __restrict__ nuniq) {
  int i = blockIdx.x * blockDim.x + threadIdx.x;
  if (i < N_NODES) flags[i] = 0;
  if (i < BATCH) cursor[i] = 0;
  if (i == 0) *nuniq = 0;
}

__global__ void mark_needed_kernel(const int* __restrict__ idx, int* __restrict__ flags) {
  int i = blockIdx.x * blockDim.x + threadIdx.x;
  if (i < BATCH) {
    int id = idx[i];
    if (id >= 0) flags[id] = 1;
  }
}

__global__ void assign_slots_kernel(const int* __restrict__ flags, int* __restrict__ slot,
                                    int* __restrict__ uniq, int* __restrict__ nuniq) {
  int i = blockIdx.x * blockDim.x + threadIdx.x;
  if (i >= N_NODES) return;
  if (flags[i]) {
    int s = atomicAdd(nuniq, 1);
    slot[i] = s;
    uniq[s] = i;
  }
}

__global__ __launch_bounds__(256) void fill_edges_kernel(
    const int* __restrict__ ei, const float* __restrict__ ew,
    const int* __restrict__ flags, const int* __restrict__ slot,
    int* __restrict__ cursor, int* __restrict__ el_src, float* __restrict__ el_w) {
  int e = blockIdx.x * blockDim.x + threadIdx.x;
  if (e >= N_EDGES) return;
  int dst = ei[N_EDGES + e];
  if (!flags[dst]) return;
  int s = slot[dst];
  int p = atomicAdd(&cursor[s], 1);
  if (p < MAXDEG) {
    el_src[s * MAXDEG + p] = ei[e];
    el_w[s * MAXDEG + p] = ew[e];
  }
}

__global__ __launch_bounds__(256) void gather_nodes_kernel(
    const float* __restrict__ cache, const int* __restrict__ uniq,
    const int* __restrict__ cursor, const int* __restrict__ nuniq,
    const int* __restrict__ el_src, const float* __restrict__ el_w,
    bf16* __restrict__ compact2) {
  int s = blockIdx.x, t = threadIdx.x;
  bf16* row = compact2 + (size_t)s * (2 * GNN_D);
  if (s >= *nuniq) {
    row[t] = __float2bfloat16(0.f);
    row[GNN_D + t] = __float2bfloat16(0.f);
    return;
  }
  row[t] = __float2bfloat16(cache[(size_t)uniq[s] * GNN_D + t]);
  int deg = cursor[s];
  deg = (deg < MAXDEG) ? deg : MAXDEG;
  float acc = 0.f;
  for (int e = 0; e < deg; ++e) {
    int src = el_src[s * MAXDEG + e];
    float w = el_w[s * MAXDEG + e];
    acc += cache[(size_t)src * GNN_D + t] * w;
  }
  row[GNN_D + t] = __float2bfloat16(acc);
}

__global__ __launch_bounds__(256) void gather_ln_kernel(
    const float* __restrict__ embc, const int* __restrict__ slot,
    const float* __restrict__ fallback, const int* __restrict__ idx,
    const float* __restrict__ scale, const float* __restrict__ bias,
    bf16* __restrict__ out) {
  int b = blockIdx.x, t = threadIdx.x;
  int id = idx[b];
  float v = (id >= 0) ? embc[(size_t)slot[id] * GNN_D + t] : fallback[t];
  float s = v, q = v * v;
#pragma unroll
  for (int o = 32; o > 0; o >>= 1) { s += __shfl_down(s, o); q += __shfl_down(q, o); }
  __shared__ float ls[4], lq[4];
  int wv = t >> 6, ln = t & 63;
  if (ln == 0) { ls[wv] = s; lq[wv] = q; }
  __syncthreads();
  s = ls[0] + ls[1] + ls[2] + ls[3];
  q = lq[0] + lq[1] + lq[2] + lq[3];
  float mu = s * (1.f / GNN_D);
  float var = q * (1.f / GNN_D) - mu * mu;
  float r = rsqrtf(var + LN_EPS);
  out[(size_t)b * GNN_D + t] = __float2bfloat16((v - mu) * r * scale[t] + bias[t]);
}

__global__ __launch_bounds__(256) void ln512_kernel(
    const float* __restrict__ x, const float* __restrict__ scale,
    const float* __restrict__ bias, bf16* __restrict__ out) {
  int b = blockIdx.x, t = threadIdx.x;
  const float* xr = x + (size_t)b * H_D;
  float v0 = xr[t];
  float v1 = xr[256 + t];
  float s = v0 + v1, q = v0 * v0 + v1 * v1;
#pragma unroll
  for (int o = 32; o > 0; o >>= 1) { s += __shfl_down(s, o); q += __shfl_down(q, o); }
  __shared__ float ls[4], lq[4];
  int wv = t >> 6, ln = t & 63;
  if (ln == 0) { ls[wv] = s; lq[wv] = q; }
  __syncthreads();
  s = ls[0] + ls[1] + ls[2] + ls[3];
  q = lq[0] + lq[1] + lq[2] + lq[3];
  float mu = s * (1.f / H_D);
  float var = q * (1.f / H_D) - mu * mu;
  float r = rsqrtf(var + LN_EPS);
  bf16* orow = out + (size_t)b * H_D;
  orow[t]       = __float2bfloat16((v0 - mu) * r * scale[t]       + bias[t]);
  orow[256 + t] = __float2bfloat16((v1 - mu) * r * scale[256 + t] + bias[256 + t]);
}

__device__ inline float gelu_exact(float x) {
  return 0.5f * x * (1.f + erff(x * 0.70710678118654752f));
}

// ---------------- bf16 MFMA GEMM: C = act(A @ W^T [+ bias] [+ addC]) ----------------
// Round-6 proven structure (best verified: 625.6 us total). A:[M,K], W:[N,K] bf16
// row-major. BM=NBM*64, BN=NBN*64; WRxWC waves; wave owns (BM/WR)x(BN/WC).
// 2-phase double-buffered K-loop: issue next-tile global_load_lds into buf^1 BEFORE
// ds_read+MFMA of buf; single vmcnt(0)+barrier per K-step (__syncthreads).
// [Rounds 7/8/9 tested counted-vmcnt 3-buf, fused-LN reg-staging, KSTEP=64 — all
//  regressed vs this structure; see session journal.]

template <int WR, int WC, int NBM, int NBN, int ACT, int OUT_BF16, int ADDC, int BIAS,
          int HBF, int SWZ>
__global__ __launch_bounds__(WR * WC * 64) void gemm_mfma_kernel(
    const bf16* __restrict__ A, const bf16* __restrict__ W,
    const float* __restrict__ bias, const float* __restrict__ addC,
    void* __restrict__ Cout, bf16* __restrict__ out2,
    int M, int N, int K, int gx) {
  constexpr int THREADS = WR * WC * 64;
  constexpr int BM = NBM * 64;
  constexpr int BN = NBN * 64;
  constexpr int MR = BM / (WR * 16);   // m-frags per wave
  constexpr int NR = BN / (WC * 16);   // n-frags per wave
  constexpr int ITA = (BM * 4) / THREADS;  // A staging iters (16B chunks)
  constexpr int ITB = (BN * 4) / THREADS;
  __shared__ __align__(16) bf16 sA[2][BM * 32];
  __shared__ __align__(16) bf16 sB[2][BN * 32];
  const int tid = threadIdx.x;
  const int lane = tid & 63;
  const int wid = tid >> 6;
  const int wr = wid / WC, wc = wid % WC;

  int bidx, bidy;
  if (SWZ) {
    // chunked XCD map (nwg % 8 == 0): each XCD gets a contiguous chunk;
    // bidx (M) varies fastest within the chunk -> B-panel stays L2-resident.
    int nwg = gridDim.x;
    int bid = blockIdx.x;
    int l = (bid & 7) * (nwg >> 3) + (bid >> 3);
    bidx = l % gx;
    bidy = l / gx;
  } else {
    bidx = blockIdx.x;
    bidy = blockIdx.y;
  }
  const int bm = bidx * BM, bn = bidy * BN;

  f32x4 acc[MR][NR];
#pragma unroll
  for (int m = 0; m < MR; ++m)
#pragma unroll
    for (int n = 0; n < NR; ++n) acc[m][n] = (f32x4){0.f, 0.f, 0.f, 0.f};

  const int rbase = lane & 15;
  const int g = lane >> 4;
  const int kq = (tid & 3) << 3;    // per-thread k offset within 32-chunk

  int arow[ITA], brow[ITB];
#pragma unroll
  for (int i = 0; i < ITA; ++i) {
    int r0 = bm + ((i * THREADS + tid) >> 2);
    arow[i] = (r0 < M) ? r0 : (M - 1);
  }
#pragma unroll
  for (int i = 0; i < ITB; ++i) {
    int r0 = bn + ((i * THREADS + tid) >> 2);
    brow[i] = (r0 < N) ? r0 : (N - 1);
  }

  auto stage = [&](int buf, int k0) {
#pragma unroll
    for (int i = 0; i < ITA; ++i)
      __builtin_amdgcn_global_load_lds(
          (const __attribute__((address_space(1))) void*)(A + (size_t)arow[i] * K + k0 + kq),
          (__attribute__((address_space(3))) void*)(&sA[buf][(i * THREADS + tid) * 8]), 16, 0, 0);
#pragma unroll
    for (int i = 0; i < ITB; ++i)
      __builtin_amdgcn_global_load_lds(
          (const __attribute__((address_space(1))) void*)(W + (size_t)brow[i] * K + k0 + kq),
          (__attribute__((address_space(3))) void*)(&sB[buf][(i * THREADS + tid) * 8]), 16, 0, 0);
  };

  const int NT = K >> 5;
  stage(0, 0);
  __syncthreads();               // drain prologue stage

  int cur = 0;
  for (int t = 0; t < NT; ++t) {
    if (t + 1 < NT) stage(cur ^ 1, (t + 1) << 5);   // issue next tile early

    short8 af[MR], bfrag[NR];
#pragma unroll
    for (int m = 0; m < MR; ++m)
      af[m] = *(const short8*)(&sA[cur][(wr * (BM / WR) + m * 16 + rbase) * 32 + g * 8]);
#pragma unroll
    for (int n = 0; n < NR; ++n)
      bfrag[n] = *(const short8*)(&sB[cur][(wc * (BN / WC) + n * 16 + rbase) * 32 + g * 8]);
#pragma unroll
    for (int m = 0; m < MR; ++m)
#pragma unroll
      for (int n = 0; n < NR; ++n)
        acc[m][n] = __builtin_amdgcn_mfma_f32_16x16x32_bf16(af[m], bfrag[n], acc[m][n], 0, 0, 0);

    __syncthreads();             // one vmcnt(0)+barrier per K-step
    cur ^= 1;
  }

  // C/D frag mapping: col = lane&15, row = (lane>>4)*4 + reg   [m89-verified]
  const int rb = (lane >> 4) * 4;
  const int cb = lane & 15;
#pragma unroll
  for (int m = 0; m < MR; ++m) {
#pragma unroll
    for (int n = 0; n < NR; ++n) {
      int col = bn + wc * (BN / WC) + n * 16 + cb;
      if (col >= N) continue;
      int row0 = bm + wr * (BM / WR) + m * 16 + rb;
#pragma unroll
      for (int r = 0; r < 4; ++r) {
        int row = row0 + r;
        if (row >= M) continue;
        float v = acc[m][n][r];
        if (BIAS) v += bias[col];
        if (ADDC) v += addC[(size_t)row * N + col];
        if (ACT == 1) v = fmaxf(v, 0.f);
        if (ACT == 2) v = gelu_exact(v);
        if (OUT_BF16)
          ((bf16*)Cout)[(size_t)row * N + col] = __float2bfloat16(v);
        else
          ((float*)Cout)[(size_t)row * N + col] = v;
        if (HBF)
          out2[(size_t)row * N + col] = __float2bfloat16(v);
      }
    }
  }
}

template <int WR, int WC, int NBM, int NBN, int ACT, int OUT_BF16, int ADDC, int BIAS, int HBF>
static void launch_mfma(const bf16* A, const bf16* W, const float* bias,
                        const float* addC, void* C, bf16* out2,
                        int M, int N, int K, hipStream_t stream) {
  dim3 grid(M / (NBM * 64), (N + NBN * 64 - 1) / (NBN * 64));
  gemm_mfma_kernel<WR, WC, NBM, NBN, ACT, OUT_BF16, ADDC, BIAS, HBF, 0>
      <<<grid, WR * WC * 64, 0, stream>>>(A, W, bias, addC, C, out2, M, N, K, 0);
}

// ---------------- launch ----------------

#define MB (1024u * 1024u)

extern "C" void kernel_launch(void* const* d_in, const int* in_sizes, int n_in,
                              void* d_out, int out_size, void* d_ws, size_t ws_size,
                              hipStream_t stream) {
  const int*   node_indices = (const int*)d_in[0];
  const int*   edge_index   = (const int*)d_in[1];
  const float* edge_weight  = (const float*)d_in[2];
  const float* cache        = (const float*)d_in[3];
  const float* w_root       = (const float*)d_in[4];
  const float* w_neigh      = (const float*)d_in[5];
  const float* w_post       = (const float*)d_in[6];
  const float* b_post       = (const float*)d_in[7];
  const float* fallback     = (const float*)d_in[8];
  const float* ln_in_scale  = (const float*)d_in[9];
  const float* ln_in_bias   = (const float*)d_in[10];
  const float* w_in         = (const float*)d_in[11];
  const float* rb_ln_scale  = (const float*)d_in[12];
  const float* rb_ln_bias   = (const float*)d_in[13];
  const float* rb_fc1       = (const float*)d_in[14];
  const float* rb_fc2       = (const float*)d_in[15];
  const float* w_bil        = (const float*)d_in[16];
  const float* gene         = (const float*)d_in[17];
  float* out = (float*)d_out;

  char* w = (char*)d_ws;
  // --- region A (0..24 MB): graph-stage buffers, dead after gather_ln; ymid aliases ---
  bf16*  compact2 = (bf16*)(w + 0 * MB);   // 4 MB
  bf16*  tmpc     = (bf16*)(w + 4 * MB);   // 2 MB
  float* embc     = (float*)(w + 6 * MB);  // 4 MB
  int*   el_src   = (int*)  (w + 10 * MB); // 2 MB
  float* el_w     = (float*)(w + 12 * MB); // 2 MB
  int*   flags    = (int*)  (w + 14 * MB);
  int*   slot     = (int*)  (w + 14 * MB + 80 * 1024);
  int*   uniq     = (int*)  (w + 14 * MB + 160 * 1024);
  int*   cursor   = (int*)  (w + 14 * MB + 180 * 1024);
  int*   nuniq    = (int*)  (w + 14 * MB + 200 * 1024);
  bf16*  ymid     = (bf16*) (w + 0 * MB);  // 16 MB (phase-4 only, region A dead)
  // --- region B (24 MB..): activations + bf16 weights ---
  bf16*  pertln  = (bf16*) (w + 24 * MB);
  float* h       = (float*)(w + 26 * MB);
  bf16*  yln     = (bf16*) (w + 34 * MB);
  bf16*  h_bf    = (bf16*) (w + 38 * MB);
  bf16*  blin    = (bf16*) (w + 42 * MB);
  bf16*  w_in_bf = (bf16*) (w + 55 * MB);
  bf16*  fc1_bf  = (bf16*) (w + 56 * MB);
  bf16*  fc2_bf  = (bf16*) (w + 68 * MB);
  bf16*  wbil_bf = (bf16*) (w + 80 * MB);
  bf16*  gene_bf = (bf16*) (w + 82 * MB);
  bf16*  wrn_bf  = (bf16*) (w + 90 * MB);
  bf16*  wpost_bf= (bf16*) (w + 91 * MB);

  // 0) all weight conversions in ONE kernel
  convert_weights_kernel<<<(CONV_TOT + 255) / 256, 256, 0, stream>>>(
      w_in, rb_fc1, rb_fc2, w_bil, gene, w_post, w_root, w_neigh,
      w_in_bf, fc1_bf, fc2_bf, wbil_bf, gene_bf, wpost_bf, wrn_bf);

  // 1) compact-slot construction + bucketed edge lists + gather-accumulate (bf16 out)
  init_meta_kernel<<<(N_NODES + 255) / 256, 256, 0, stream>>>(flags, cursor, nuniq);
  mark_needed_kernel<<<(BATCH + 255) / 256, 256, 0, stream>>>(node_indices, flags);
  assign_slots_kernel<<<(N_NODES + 255) / 256, 256, 0, stream>>>(flags, slot, uniq, nuniq);
  fill_edges_kernel<<<(N_EDGES + 255) / 256, 256, 0, stream>>>(
      edge_index, edge_weight, flags, slot, cursor, el_src, el_w);
  gather_nodes_kernel<<<BATCH, 256, 0, stream>>>(
      cache, uniq, cursor, nuniq, el_src, el_w, compact2);

  // 2) compact graph tail (bf16 MFMA, 64x64): relu([cache|agg]@[wr|wn]^T) @ w_post^T + b
  launch_mfma<2, 2, 1, 1, 1, 1, 0, 0, 0>(compact2, wrn_bf, nullptr, nullptr, tmpc, nullptr,
                                         BATCH, GNN_D, 2 * GNN_D, stream);
  launch_mfma<2, 2, 1, 1, 0, 0, 0, 1, 0>(tmpc, wpost_bf, b_post, nullptr, embc, nullptr,
                                         BATCH, GNN_D, GNN_D, stream);

  // 3) gather + input LN (bf16 out), input proj (64x64) -> h fp32
  gather_ln_kernel<<<BATCH, 256, 0, stream>>>(embc, slot, fallback, node_indices,
                                              ln_in_scale, ln_in_bias, pertln);
  launch_mfma<2, 2, 1, 1, 0, 0, 0, 0, 0>(pertln, w_in_bf, nullptr, nullptr, h, nullptr,
                                         BATCH, H_D, GNN_D, stream);

  // 4) residual blocks: LN -> fc1(gelu, bf16, 128x128) -> fc2(+h, fp32, 64x64)
  for (int i = 0; i < L_N; ++i) {
    ln512_kernel<<<BATCH, 256, 0, stream>>>(h, rb_ln_scale + (size_t)i * H_D,
                                            rb_ln_bias + (size_t)i * H_D, yln);
    launch_mfma<2, 2, 2, 2, 2, 1, 0, 0, 0>(yln, fc1_bf + (size_t)i * MID_D * H_D,
                                           nullptr, nullptr, ymid, nullptr,
                                           BATCH, MID_D, H_D, stream);
    if (i < L_N - 1)
      launch_mfma<2, 2, 1, 1, 0, 0, 1, 0, 0>(ymid, fc2_bf + (size_t)i * H_D * MID_D,
                                             nullptr, h, h, nullptr,
                                             BATCH, H_D, MID_D, stream);
    else  // last layer: also emit bf16 h for the bilinear head
      launch_mfma<2, 2, 1, 1, 0, 0, 1, 0, 1>(ymid, fc2_bf + (size_t)i * H_D * MID_D,
                                             nullptr, h, h, h_bf,
                                             BATCH, H_D, MID_D, stream);
  }

  // 5) bilinear head (64x128, bf16 out) + gene einsum (8-wave 256x256, fp32 out,
  //    chunked-XCD 1D grid: bidx fast within each XCD chunk)
  launch_mfma<2, 2, 1, 2, 0, 1, 0, 0, 0>(h_bf, wbil_bf, nullptr, nullptr, blin, nullptr,
                                         BATCH, C_N * R_D, H_D, stream);
  {
    int gx = (BATCH * C_N) / 256;            // 48
    int gy = (G_N + 255) / 256;              // 26
    int nwg = gx * gy;                       // 1248 (divisible by 8)
    gemm_mfma_kernel<2, 4, 4, 4, 0, 0, 0, 0, 0, 1><<<nwg, 512, 0, stream>>>(
        blin, gene_bf, nullptr, nullptr, out, nullptr, BATCH * C_N, G_N, R_D, gx);
  }
}

// Round 13
// 627.177 us; speedup vs baseline: 1.0571x; 1.0009x over previous
//
#include <hip/hip_runtime.h>
#include <hip/hip_bf16.h>

#define N_NODES 19000
#define N_EDGES 600000
#define BATCH   4096
#define GNN_D   256
#define H_D     512
#define MID_D   2048
#define L_N     6
#define C_N     3
#define R_D     512
#define G_N     6640
#define LN_EPS  1e-5f
#define MAXDEG  128

typedef __attribute__((ext_vector_type(8))) short short8;
typedef __attribute__((ext_vector_type(4))) float f32x4;
typedef __hip_bfloat16 bf16;

// ---------------- merged weight conversion (7 dsts, 1 launch) ----------------
#define SEG0 32768                    // w_in   512*256/4
#define SEG1 (SEG0 + 1572864)         // fc1    6*2048*512/4
#define SEG2 (SEG1 + 1572864)         // fc2
#define SEG3 (SEG2 + 196608)          // wbil   3*512*512/4
#define SEG4 (SEG3 + 849920)          // gene   6640*512/4
#define SEG5 (SEG4 + 16384)           // wpost  256*256/4
#define SEG6 (SEG5 + 32768)           // wrn    256*512/4
#define CONV_TOT SEG6

__global__ void convert_weights_kernel(
    const float* __restrict__ w_in, const float* __restrict__ fc1,
    const float* __restrict__ fc2, const float* __restrict__ wbil,
    const float* __restrict__ gene, const float* __restrict__ wpost,
    const float* __restrict__ wroot, const float* __restrict__ wneigh,
    bf16* __restrict__ o_win, bf16* __restrict__ o_fc1, bf16* __restrict__ o_fc2,
    bf16* __restrict__ o_wbil, bf16* __restrict__ o_gene, bf16* __restrict__ o_wpost,
    bf16* __restrict__ o_wrn) {
  int i = blockIdx.x * blockDim.x + threadIdx.x;
  if (i >= CONV_TOT) return;
  const float* src;
  bf16* dst;
  if (i < SEG0)      { src = w_in  + (size_t)i * 4;            dst = o_win  + (size_t)i * 4; }
  else if (i < SEG1) { size_t j = i - SEG0; src = fc1  + j * 4; dst = o_fc1  + j * 4; }
  else if (i < SEG2) { size_t j = i - SEG1; src = fc2  + j * 4; dst = o_fc2  + j * 4; }
  else if (i < SEG3) { size_t j = i - SEG2; src = wbil + j * 4; dst = o_wbil + j * 4; }
  else if (i < SEG4) { size_t j = i - SEG3; src = gene + j * 4; dst = o_gene + j * 4; }
  else if (i < SEG5) { size_t j = i - SEG4; src = wpost+ j * 4; dst = o_wpost+ j * 4; }
  else {  // wrn: [256][512] = [w_root | w_neigh]
    int j = i - SEG5;
    int base = j * 4;
    int n = base >> 9;
    int k = base & 511;
    src = (k < GNN_D) ? (wroot + (size_t)n * GNN_D + k)
                      : (wneigh + (size_t)n * GNN_D + (k - GNN_D));
    dst = o_wrn + base;
  }
  float4 v = *(const float4*)src;
  dst[0] = __float2bfloat16(v.x);
  dst[1] = __float2bfloat16(v.y);
  dst[2] = __float2bfloat16(v.z);
  dst[3] = __float2bfloat16(v.w);
}

// ---------------- graph compaction kernels (unchanged, proven) ----------------

__global__ void init_meta_kernel(int* __restrict__ flags, int* __restrict__ cursor,
                                 int* __restrict__ nuniq) {
  int i = blockIdx.x * blockDim.x + threadIdx.x;
  if (i < N_NODES) flags[i] = 0;
  if (i < BATCH) cursor[i] = 0;
  if (i == 0) *nuniq = 0;
}

__global__ void mark_needed_kernel(const int* __restrict__ idx, int* __restrict__ flags) {
  int i = blockIdx.x * blockDim.x + threadIdx.x;
  if (i < BATCH) {
    int id = idx[i];
    if (id >= 0) flags[id] = 1;
  }
}

__global__ void assign_slots_kernel(const int* __restrict__ flags, int* __restrict__ slot,
                                    int* __restrict__ uniq, int* __restrict__ nuniq) {
  int i = blockIdx.x * blockDim.x + threadIdx.x;
  if (i >= N_NODES) return;
  if (flags[i]) {
    int s = atomicAdd(nuniq, 1);
    slot[i] = s;
    uniq[s] = i;
  }
}

__global__ __launch_bounds__(256) void fill_edges_kernel(
    const int* __restrict__ ei, const float* __restrict__ ew,
    const int* __restrict__ flags, const int* __restrict__ slot,
    int* __restrict__ cursor, int* __restrict__ el_src, float* __restrict__ el_w) {
  int e = blockIdx.x * blockDim.x + threadIdx.x;
  if (e >= N_EDGES) return;
  int dst = ei[N_EDGES + e];
  if (!flags[dst]) return;
  int s = slot[dst];
  int p = atomicAdd(&cursor[s], 1);
  if (p < MAXDEG) {
    el_src[s * MAXDEG + p] = ei[e];
    el_w[s * MAXDEG + p] = ew[e];
  }
}

__global__ __launch_bounds__(256) void gather_nodes_kernel(
    const float* __restrict__ cache, const int* __restrict__ uniq,
    const int* __restrict__ cursor, const int* __restrict__ nuniq,
    const int* __restrict__ el_src, const float* __restrict__ el_w,
    bf16* __restrict__ compact2) {
  int s = blockIdx.x, t = threadIdx.x;
  bf16* row = compact2 + (size_t)s * (2 * GNN_D);
  if (s >= *nuniq) {
    row[t] = __float2bfloat16(0.f);
    row[GNN_D + t] = __float2bfloat16(0.f);
    return;
  }
  row[t] = __float2bfloat16(cache[(size_t)uniq[s] * GNN_D + t]);
  int deg = cursor[s];
  deg = (deg < MAXDEG) ? deg : MAXDEG;
  float acc = 0.f;
  for (int e = 0; e < deg; ++e) {
    int src = el_src[s * MAXDEG + e];
    float w = el_w[s * MAXDEG + e];
    acc += cache[(size_t)src * GNN_D + t] * w;
  }
  row[GNN_D + t] = __float2bfloat16(acc);
}

__global__ __launch_bounds__(256) void gather_ln_kernel(
    const float* __restrict__ embc, const int* __restrict__ slot,
    const float* __restrict__ fallback, const int* __restrict__ idx,
    const float* __restrict__ scale, const float* __restrict__ bias,
    bf16* __restrict__ out) {
  int b = blockIdx.x, t = threadIdx.x;
  int id = idx[b];
  float v = (id >= 0) ? embc[(size_t)slot[id] * GNN_D + t] : fallback[t];
  float s = v, q = v * v;
#pragma unroll
  for (int o = 32; o > 0; o >>= 1) { s += __shfl_down(s, o); q += __shfl_down(q, o); }
  __shared__ float ls[4], lq[4];
  int wv = t >> 6, ln = t & 63;
  if (ln == 0) { ls[wv] = s; lq[wv] = q; }
  __syncthreads();
  s = ls[0] + ls[1] + ls[2] + ls[3];
  q = lq[0] + lq[1] + lq[2] + lq[3];
  float mu = s * (1.f / GNN_D);
  float var = q * (1.f / GNN_D) - mu * mu;
  float r = rsqrtf(var + LN_EPS);
  out[(size_t)b * GNN_D + t] = __float2bfloat16((v - mu) * r * scale[t] + bias[t]);
}

__global__ __launch_bounds__(256) void ln512_kernel(
    const float* __restrict__ x, const float* __restrict__ scale,
    const float* __restrict__ bias, bf16* __restrict__ out) {
  int b = blockIdx.x, t = threadIdx.x;
  const float* xr = x + (size_t)b * H_D;
  float v0 = xr[t];
  float v1 = xr[256 + t];
  float s = v0 + v1, q = v0 * v0 + v1 * v1;
#pragma unroll
  for (int o = 32; o > 0; o >>= 1) { s += __shfl_down(s, o); q += __shfl_down(q, o); }
  __shared__ float ls[4], lq[4];
  int wv = t >> 6, ln = t & 63;
  if (ln == 0) { ls[wv] = s; lq[wv] = q; }
  __syncthreads();
  s = ls[0] + ls[1] + ls[2] + ls[3];
  q = lq[0] + lq[1] + lq[2] + lq[3];
  float mu = s * (1.f / H_D);
  float var = q * (1.f / H_D) - mu * mu;
  float r = rsqrtf(var + LN_EPS);
  bf16* orow = out + (size_t)b * H_D;
  orow[t]       = __float2bfloat16((v0 - mu) * r * scale[t]       + bias[t]);
  orow[256 + t] = __float2bfloat16((v1 - mu) * r * scale[256 + t] + bias[256 + t]);
}

__device__ inline float gelu_exact(float x) {
  return 0.5f * x * (1.f + erff(x * 0.70710678118654752f));
}

// ---------------- bf16 MFMA GEMM: C = act(A @ W^T [+ bias] [+ addC]) ----------------
// Round-6 proven structure (best verified: 625.6 us total). A:[M,K], W:[N,K] bf16
// row-major. BM=NBM*64, BN=NBN*64; WRxWC waves; wave owns (BM/WR)x(BN/WC).
// 2-phase double-buffered K-loop: issue next-tile global_load_lds into buf^1 BEFORE
// ds_read+MFMA of buf; single vmcnt(0)+barrier per K-step (__syncthreads).
// [Rounds 7/8/9 tested counted-vmcnt 3-buf, fused-LN reg-staging, KSTEP=64 — all
//  regressed vs this structure. Round 11's merged-init + bf16-cache variant diverged
//  post-replay — reverted. This is the final, twice-verified configuration.]

template <int WR, int WC, int NBM, int NBN, int ACT, int OUT_BF16, int ADDC, int BIAS,
          int HBF, int SWZ>
__global__ __launch_bounds__(WR * WC * 64) void gemm_mfma_kernel(
    const bf16* __restrict__ A, const bf16* __restrict__ W,
    const float* __restrict__ bias, const float* __restrict__ addC,
    void* __restrict__ Cout, bf16* __restrict__ out2,
    int M, int N, int K, int gx) {
  constexpr int THREADS = WR * WC * 64;
  constexpr int BM = NBM * 64;
  constexpr int BN = NBN * 64;
  constexpr int MR = BM / (WR * 16);   // m-frags per wave
  constexpr int NR = BN / (WC * 16);   // n-frags per wave
  constexpr int ITA = (BM * 4) / THREADS;  // A staging iters (16B chunks)
  constexpr int ITB = (BN * 4) / THREADS;
  __shared__ __align__(16) bf16 sA[2][BM * 32];
  __shared__ __align__(16) bf16 sB[2][BN * 32];
  const int tid = threadIdx.x;
  const int lane = tid & 63;
  const int wid = tid >> 6;
  const int wr = wid / WC, wc = wid % WC;

  int bidx, bidy;
  if (SWZ) {
    // chunked XCD map (nwg % 8 == 0): each XCD gets a contiguous chunk;
    // bidx (M) varies fastest within the chunk -> B-panel stays L2-resident.
    int nwg = gridDim.x;
    int bid = blockIdx.x;
    int l = (bid & 7) * (nwg >> 3) + (bid >> 3);
    bidx = l % gx;
    bidy = l / gx;
  } else {
    bidx = blockIdx.x;
    bidy = blockIdx.y;
  }
  const int bm = bidx * BM, bn = bidy * BN;

  f32x4 acc[MR][NR];
#pragma unroll
  for (int m = 0; m < MR; ++m)
#pragma unroll
    for (int n = 0; n < NR; ++n) acc[m][n] = (f32x4){0.f, 0.f, 0.f, 0.f};

  const int rbase = lane & 15;
  const int g = lane >> 4;
  const int kq = (tid & 3) << 3;    // per-thread k offset within 32-chunk

  int arow[ITA], brow[ITB];
#pragma unroll
  for (int i = 0; i < ITA; ++i) {
    int r0 = bm + ((i * THREADS + tid) >> 2);
    arow[i] = (r0 < M) ? r0 : (M - 1);
  }
#pragma unroll
  for (int i = 0; i < ITB; ++i) {
    int r0 = bn + ((i * THREADS + tid) >> 2);
    brow[i] = (r0 < N) ? r0 : (N - 1);
  }

  auto stage = [&](int buf, int k0) {
#pragma unroll
    for (int i = 0; i < ITA; ++i)
      __builtin_amdgcn_global_load_lds(
          (const __attribute__((address_space(1))) void*)(A + (size_t)arow[i] * K + k0 + kq),
          (__attribute__((address_space(3))) void*)(&sA[buf][(i * THREADS + tid) * 8]), 16, 0, 0);
#pragma unroll
    for (int i = 0; i < ITB; ++i)
      __builtin_amdgcn_global_load_lds(
          (const __attribute__((address_space(1))) void*)(W + (size_t)brow[i] * K + k0 + kq),
          (__attribute__((address_space(3))) void*)(&sB[buf][(i * THREADS + tid) * 8]), 16, 0, 0);
  };

  const int NT = K >> 5;
  stage(0, 0);
  __syncthreads();               // drain prologue stage

  int cur = 0;
  for (int t = 0; t < NT; ++t) {
    if (t + 1 < NT) stage(cur ^ 1, (t + 1) << 5);   // issue next tile early

    short8 af[MR], bfrag[NR];
#pragma unroll
    for (int m = 0; m < MR; ++m)
      af[m] = *(const short8*)(&sA[cur][(wr * (BM / WR) + m * 16 + rbase) * 32 + g * 8]);
#pragma unroll
    for (int n = 0; n < NR; ++n)
      bfrag[n] = *(const short8*)(&sB[cur][(wc * (BN / WC) + n * 16 + rbase) * 32 + g * 8]);
#pragma unroll
    for (int m = 0; m < MR; ++m)
#pragma unroll
      for (int n = 0; n < NR; ++n)
        acc[m][n] = __builtin_amdgcn_mfma_f32_16x16x32_bf16(af[m], bfrag[n], acc[m][n], 0, 0, 0);

    __syncthreads();             // one vmcnt(0)+barrier per K-step
    cur ^= 1;
  }

  // C/D frag mapping: col = lane&15, row = (lane>>4)*4 + reg   [m89-verified]
  const int rb = (lane >> 4) * 4;
  const int cb = lane & 15;
#pragma unroll
  for (int m = 0; m < MR; ++m) {
#pragma unroll
    for (int n = 0; n < NR; ++n) {
      int col = bn + wc * (BN / WC) + n * 16 + cb;
      if (col >= N) continue;
      int row0 = bm + wr * (BM / WR) + m * 16 + rb;
#pragma unroll
      for (int r = 0; r < 4; ++r) {
        int row = row0 + r;
        if (row >= M) continue;
        float v = acc[m][n][r];
        if (BIAS) v += bias[col];
        if (ADDC) v += addC[(size_t)row * N + col];
        if (ACT == 1) v = fmaxf(v, 0.f);
        if (ACT == 2) v = gelu_exact(v);
        if (OUT_BF16)
          ((bf16*)Cout)[(size_t)row * N + col] = __float2bfloat16(v);
        else
          ((float*)Cout)[(size_t)row * N + col] = v;
        if (HBF)
          out2[(size_t)row * N + col] = __float2bfloat16(v);
      }
    }
  }
}

template <int WR, int WC, int NBM, int NBN, int ACT, int OUT_BF16, int ADDC, int BIAS, int HBF>
static void launch_mfma(const bf16* A, const bf16* W, const float* bias,
                        const float* addC, void* C, bf16* out2,
                        int M, int N, int K, hipStream_t stream) {
  dim3 grid(M / (NBM * 64), (N + NBN * 64 - 1) / (NBN * 64));
  gemm_mfma_kernel<WR, WC, NBM, NBN, ACT, OUT_BF16, ADDC, BIAS, HBF, 0>
      <<<grid, WR * WC * 64, 0, stream>>>(A, W, bias, addC, C, out2, M, N, K, 0);
}

// ---------------- launch ----------------

#define MB (1024u * 1024u)

extern "C" void kernel_launch(void* const* d_in, const int* in_sizes, int n_in,
                              void* d_out, int out_size, void* d_ws, size_t ws_size,
                              hipStream_t stream) {
  const int*   node_indices = (const int*)d_in[0];
  const int*   edge_index   = (const int*)d_in[1];
  const float* edge_weight  = (const float*)d_in[2];
  const float* cache        = (const float*)d_in[3];
  const float* w_root       = (const float*)d_in[4];
  const float* w_neigh      = (const float*)d_in[5];
  const float* w_post       = (const float*)d_in[6];
  const float* b_post       = (const float*)d_in[7];
  const float* fallback     = (const float*)d_in[8];
  const float* ln_in_scale  = (const float*)d_in[9];
  const float* ln_in_bias   = (const float*)d_in[10];
  const float* w_in         = (const float*)d_in[11];
  const float* rb_ln_scale  = (const float*)d_in[12];
  const float* rb_ln_bias   = (const float*)d_in[13];
  const float* rb_fc1       = (const float*)d_in[14];
  const float* rb_fc2       = (const float*)d_in[15];
  const float* w_bil        = (const float*)d_in[16];
  const float* gene         = (const float*)d_in[17];
  float* out = (float*)d_out;

  char* w = (char*)d_ws;
  // --- region A (0..24 MB): graph-stage buffers, dead after gather_ln; ymid aliases ---
  bf16*  compact2 = (bf16*)(w + 0 * MB);   // 4 MB
  bf16*  tmpc     = (bf16*)(w + 4 * MB);   // 2 MB
  float* embc     = (float*)(w + 6 * MB);  // 4 MB
  int*   el_src   = (int*)  (w + 10 * MB); // 2 MB
  float* el_w     = (float*)(w + 12 * MB); // 2 MB
  int*   flags    = (int*)  (w + 14 * MB);
  int*   slot     = (int*)  (w + 14 * MB + 80 * 1024);
  int*   uniq     = (int*)  (w + 14 * MB + 160 * 1024);
  int*   cursor   = (int*)  (w + 14 * MB + 180 * 1024);
  int*   nuniq    = (int*)  (w + 14 * MB + 200 * 1024);
  bf16*  ymid     = (bf16*) (w + 0 * MB);  // 16 MB (phase-4 only, region A dead)
  // --- region B (24 MB..): activations + bf16 weights ---
  bf16*  pertln  = (bf16*) (w + 24 * MB);
  float* h       = (float*)(w + 26 * MB);
  bf16*  yln     = (bf16*) (w + 34 * MB);
  bf16*  h_bf    = (bf16*) (w + 38 * MB);
  bf16*  blin    = (bf16*) (w + 42 * MB);
  bf16*  w_in_bf = (bf16*) (w + 55 * MB);
  bf16*  fc1_bf  = (bf16*) (w + 56 * MB);
  bf16*  fc2_bf  = (bf16*) (w + 68 * MB);
  bf16*  wbil_bf = (bf16*) (w + 80 * MB);
  bf16*  gene_bf = (bf16*) (w + 82 * MB);
  bf16*  wrn_bf  = (bf16*) (w + 90 * MB);
  bf16*  wpost_bf= (bf16*) (w + 91 * MB);

  // 0) all weight conversions in ONE kernel
  convert_weights_kernel<<<(CONV_TOT + 255) / 256, 256, 0, stream>>>(
      w_in, rb_fc1, rb_fc2, w_bil, gene, w_post, w_root, w_neigh,
      w_in_bf, fc1_bf, fc2_bf, wbil_bf, gene_bf, wpost_bf, wrn_bf);

  // 1) compact-slot construction + bucketed edge lists + gather-accumulate (bf16 out)
  init_meta_kernel<<<(N_NODES + 255) / 256, 256, 0, stream>>>(flags, cursor, nuniq);
  mark_needed_kernel<<<(BATCH + 255) / 256, 256, 0, stream>>>(node_indices, flags);
  assign_slots_kernel<<<(N_NODES + 255) / 256, 256, 0, stream>>>(flags, slot, uniq, nuniq);
  fill_edges_kernel<<<(N_EDGES + 255) / 256, 256, 0, stream>>>(
      edge_index, edge_weight, flags, slot, cursor, el_src, el_w);
  gather_nodes_kernel<<<BATCH, 256, 0, stream>>>(
      cache, uniq, cursor, nuniq, el_src, el_w, compact2);

  // 2) compact graph tail (bf16 MFMA, 64x64): relu([cache|agg]@[wr|wn]^T) @ w_post^T + b
  launch_mfma<2, 2, 1, 1, 1, 1, 0, 0, 0>(compact2, wrn_bf, nullptr, nullptr, tmpc, nullptr,
                                         BATCH, GNN_D, 2 * GNN_D, stream);
  launch_mfma<2, 2, 1, 1, 0, 0, 0, 1, 0>(tmpc, wpost_bf, b_post, nullptr, embc, nullptr,
                                         BATCH, GNN_D, GNN_D, stream);

  // 3) gather + input LN (bf16 out), input proj (64x64) -> h fp32
  gather_ln_kernel<<<BATCH, 256, 0, stream>>>(embc, slot, fallback, node_indices,
                                              ln_in_scale, ln_in_bias, pertln);
  launch_mfma<2, 2, 1, 1, 0, 0, 0, 0, 0>(pertln, w_in_bf, nullptr, nullptr, h, nullptr,
                                         BATCH, H_D, GNN_D, stream);

  // 4) residual blocks: LN -> fc1(gelu, bf16, 128x128) -> fc2(+h, fp32, 64x64)
  for (int i = 0; i < L_N; ++i) {
    ln512_kernel<<<BATCH, 256, 0, stream>>>(h, rb_ln_scale + (size_t)i * H_D,
                                            rb_ln_bias + (size_t)i * H_D, yln);
    launch_mfma<2, 2, 2, 2, 2, 1, 0, 0, 0>(yln, fc1_bf + (size_t)i * MID_D * H_D,
                                           nullptr, nullptr, ymid, nullptr,
                                           BATCH, MID_D, H_D, stream);
    if (i < L_N - 1)
      launch_mfma<2, 2, 1, 1, 0, 0, 1, 0, 0>(ymid, fc2_bf + (size_t)i * H_D * MID_D,
                                             nullptr, h, h, nullptr,
                                             BATCH, H_D, MID_D, stream);
    else  // last layer: also emit bf16 h for the bilinear head
      launch_mfma<2, 2, 1, 1, 0, 0, 1, 0, 1>(ymid, fc2_bf + (size_t)i * H_D * MID_D,
                                             nullptr, h, h, h_bf,
                                             BATCH, H_D, MID_D, stream);
  }

  // 5) bilinear head (64x128, bf16 out) + gene einsum (8-wave 256x256, fp32 out,
  //    chunked-XCD 1D grid: bidx fast within each XCD chunk)
  launch_mfma<2, 2, 1, 2, 0, 1, 0, 0, 0>(h_bf, wbil_bf, nullptr, nullptr, blin, nullptr,
                                         BATCH, C_N * R_D, H_D, stream);
  {
    int gx = (BATCH * C_N) / 256;            // 48
    int gy = (G_N + 255) / 256;              // 26
    int nwg = gx * gy;                       // 1248 (divisible by 8)
    gemm_mfma_kernel<2, 4, 4, 4, 0, 0, 0, 0, 0, 1><<<nwg, 512, 0, stream>>>(
        blin, gene_bf, nullptr, nullptr, out, nullptr, BATCH * C_N, G_N, R_D, gx);
  }
}